// Round 14
// baseline (262.847 us; speedup 1.0000x reference)
//
#include <hip/hip_runtime.h>
#include <hip/hip_bf16.h>
#include <hip/hip_fp16.h>
#include <stdint.h>

// BidirectionalAttention2: two flash-attention passes over sim = v1 @ v2^T.
// R14: revert R13's 4-wave blocks (regressed; occupancy unchanged). Base=R12.
//      (1) BQ=256: each wave owns TWO 16-q fragments. K/V A-fragments are
//      register-reused across both -> per-step LDS unchanged but STEPS HALVE
//      (total LDS traffic and barriers halve; MFMA/softmax totals unchanged).
//      (2) T13 defer-max (THR=8, exact): skip the 128-mul o-rescale unless
//      pmax > m+8; P bounded by e^8, fp16-safe, z-bookkeeping exact.
//      (3) vf-preload dropped (was neutral; frees regs for o[2][16]).
//      Falsifier: VGPR ~250 is tight; FETCH balloon or flash>122us -> revert.

#define MASK_FILL -1e-07f

typedef unsigned short u16;
typedef _Float16 half8 __attribute__((ext_vector_type(8)));
typedef __attribute__((ext_vector_type(4))) float f32x4;
typedef __attribute__((ext_vector_type(4))) u16 u16x4;

#define NB 64
#define LL 1024
#define DD 256
#define BQ 256
#define HB 32                 // half-block of keys (sub-tile)
#define ELEMS ((size_t)NB * LL * DD)
#define NIT_STREAM 64         // items per stream: qt(4) x dir(2) x boct(8)

__device__ __forceinline__ u16 f16b(float f) {
    _Float16 h = (_Float16)f;
    return __builtin_bit_cast(u16, h);
}
__device__ __forceinline__ unsigned pkf16(float a, float b) {
    return (unsigned)f16b(a) | ((unsigned)f16b(b) << 16);
}

__device__ __forceinline__ void gll16(const u16* g, u16* l) {
    __builtin_amdgcn_global_load_lds(
        (const __attribute__((address_space(1))) void*)g,
        (__attribute__((address_space(3))) void*)l, 16, 0, 0);
}

// ---- fused: mask dtype detect + convert + per-batch compaction + ctr clear --
__global__ __launch_bounds__(256) void prep_masks(
    const void* __restrict__ m1, const void* __restrict__ m2,
    int* __restrict__ cm1, int* __restrict__ cm2,
    int* __restrict__ qidx1, int* __restrict__ pa1, int* __restrict__ qcnt1,
    int* __restrict__ qidx2, int* __restrict__ pa2, int* __restrict__ qcnt2,
    int* __restrict__ ctr)
{
    int blk = blockIdx.x, tid = threadIdx.x;
    int msk = blk >> 6, b = blk & 63;
    const unsigned* w1 = (const unsigned*)m1;
    const unsigned* w2 = (const unsigned*)m2;
    unsigned acc = 0;
    for (int i = tid; i < 4096; i += 256) acc |= (w1[i] | w2[i]) & ~1u;
    __shared__ unsigned red[256];
    red[tid] = acc;
    __syncthreads();
    for (int o = 128; o; o >>= 1) {
        if (tid < o) red[tid] |= red[tid + o];
        __syncthreads();
    }
    int isbool = red[0] ? 1 : 0;

    const void* m = msk ? m2 : m1;
    int* cm   = msk ? cm2 : cm1;
    int* qidx = msk ? qidx2 : qidx1;
    int* pa   = msk ? pa2 : pa1;
    int* qcnt = msk ? qcnt2 : qcnt1;

    __shared__ int ps[256];
    int f[4], s = 0;
#pragma unroll
    for (int j = 0; j < 4; ++j) {
        int idx = b * LL + tid * 4 + j;
        int v = isbool ? (int)((const unsigned char*)m)[idx] : ((const int*)m)[idx];
        cm[idx] = v ? 1 : 0;
        f[j] = (v == 0) ? 1 : 0;
        s += f[j];
    }
    ps[tid] = s;
    __syncthreads();
    for (int off = 1; off < 256; off <<= 1) {
        int v = (tid >= off) ? ps[tid - off] : 0;
        __syncthreads();
        ps[tid] += v;
        __syncthreads();
    }
    int pos = (tid > 0) ? ps[tid - 1] : 0;
#pragma unroll
    for (int j = 0; j < 4; ++j) {
        pa[b * LL + tid * 4 + j] = pos;
        if (f[j]) qidx[b * LL + (pos++)] = tid * 4 + j;
    }
    if (tid == 255) qcnt[b] = ps[255];
    if (blk == 0 && tid < 8) ctr[tid] = 0;
}

// ---- prep: fp32 -> fp16 COMPACTED rows + compacted fp16 transpose +
// ---- masked-V partial sums + zeroing of masked output rows (fused) ----------
__global__ __launch_bounds__(256) void prep2_kernel(
    const float* __restrict__ x1, u16* __restrict__ h1, u16* __restrict__ t1,
    const int* __restrict__ cm1, const int* __restrict__ pa1,
    const int* __restrict__ qi1, const int* __restrict__ qc1,
    const float* __restrict__ x2, u16* __restrict__ h2, u16* __restrict__ t2,
    const int* __restrict__ cm2, const int* __restrict__ pa2,
    const int* __restrict__ qi2, const int* __restrict__ qc2,
    float* __restrict__ part, float* __restrict__ out)
{
    __shared__ u16 t[64][65];
    __shared__ float ps2[16][68];
    int blk = blockIdx.x;
    int tensor = blk >> 12;
    blk &= 4095;
    const float* x = tensor ? x2 : x1;
    u16* h  = tensor ? h2 : h1;
    u16* xt = tensor ? t2 : t1;
    const int* cm = tensor ? cm2 : cm1;
    const int* pa = tensor ? pa2 : pa1;
    const int* qi = tensor ? qi2 : qi1;
    const int* qc = tensor ? qc2 : qc1;
    float* outb = out + (tensor ? ELEMS : 0);
    int b = blk >> 6, lt = (blk >> 2) & 15, dt = blk & 3;
    int l0 = lt * 64, d0 = dt * 64;
    int tid = threadIdx.x;
    int sub = tid >> 4;
    int c16 = tid & 15;
    float vpart[4] = {0.f, 0.f, 0.f, 0.f};
#pragma unroll
    for (int p = 0; p < 4; ++p) {
        int row = p * 16 + sub;
        int l = l0 + row;
        int masked = cm[b * LL + l];
        int slot = pa[b * LL + l];
        f32x4 v = *(const f32x4*)(x + ((size_t)b * LL + l) * DD + d0 + c16 * 4);
        u16x4 hv;
#pragma unroll
        for (int e = 0; e < 4; ++e) {
            hv[e] = f16b(v[e]);
            t[c16 * 4 + e][row] = hv[e];
            if (masked) vpart[e] += v[e];
        }
        if (!masked) {
            *(u16x4*)(h + ((size_t)b * LL + slot) * DD + d0 + c16 * 4) = hv;
        } else {
            f32x4 z4 = {0.f, 0.f, 0.f, 0.f};
            *(f32x4*)(outb + ((size_t)b * LL + l) * DD + d0 + c16 * 4) = z4;
        }
    }
#pragma unroll
    for (int e = 0; e < 4; ++e) ps2[sub][c16 * 4 + e] = vpart[e];
    __syncthreads();
    // compacted transpose, slot-aligned u16x4 stores (head/tail scalar)
    int first = pa[b * LL + l0];
    int cntb = qc[b];
    int nun = ((lt == 15) ? cntb : pa[b * LL + l0 + 64]) - first;
    int last = first + nun;
    int q0 = first >> 2;
    int nq = ((last + 3) >> 2) - q0;     // <= 17 aligned quads
    const int* qib = qi + b * LL;
#pragma unroll
    for (int p = 0; p < 4; ++p) {
        int d = p * 16 + sub;
        u16* xrow = xt + ((size_t)b * DD + d0 + d) * LL;
        for (int qq = c16; qq < nq; qq += 16) {
            int s0 = (q0 + qq) << 2;
            if (s0 >= first && s0 + 4 <= last) {
                u16x4 ov;
#pragma unroll
                for (int e = 0; e < 4; ++e) {
                    int col = qib[s0 + e] - l0;
                    ov[e] = t[d][col];
                }
                *(u16x4*)(xrow + s0) = ov;
            } else {
#pragma unroll
                for (int e = 0; e < 4; ++e) {
                    int sl = s0 + e;
                    if (sl >= first && sl < last) {
                        int col = qib[sl] - l0;
                        xrow[sl] = t[d][col];
                    }
                }
            }
        }
    }
    if (tid < 64) {
        float s = 0.f;
#pragma unroll
        for (int k = 0; k < 16; ++k) s += ps2[k][tid];
        part[(((size_t)tensor * NB + b) * 16 + lt) * 256 + d0 + tid] = s;
    }
}

// ---- reduce per-tile partials -> Vsum[tensor][b][256] (fixed order) ---------
__global__ __launch_bounds__(256) void vsum_reduce(
    const float* __restrict__ part, float* __restrict__ vsum)
{
    int blk = blockIdx.x;       // tensor*NB + b
    int d = threadIdx.x;
    float s = 0.f;
#pragma unroll
    for (int lt = 0; lt < 16; ++lt)
        s += part[((size_t)blk * 16 + lt) * 256 + d];
    vsum[(size_t)blk * DD + d] = s;
}

// ---- persistent fused flash: BQ=256 (2 q-frags/wave), 64 keys/step ----------
// 256 blocks x 512 thr (1/CU). stream = blockIdx&7 -> batches b%8.
__global__ __launch_bounds__(512, 2) void flash_fused(
    const u16* __restrict__ v1h, const u16* __restrict__ v2h,
    const u16* __restrict__ v1t, const u16* __restrict__ v2t,
    const int* __restrict__ qidx1, const int* __restrict__ qcnt1,
    const int* __restrict__ qidx2, const int* __restrict__ qcnt2,
    const float* __restrict__ vsum, int* __restrict__ ctr,
    float* __restrict__ out)
{
    int strm0 = blockIdx.x & 7;
    int tid = threadIdx.x;
    int w = tid >> 6, lane = tid & 63;
    int lq = lane & 15, g = lane >> 4;

    __shared__ __align__(16) u16 khs[2][2][HB * DD];  // [key][d], chunk ^ (key&7)
    __shared__ __align__(16) u16 vts[2][2][HB * DD];  // [d][key], chunk ^ (d&3)^((d>>2)&3)

    const int pvcc = (g ^ (lq & 3) ^ ((lq >> 2) & 3)) * 8;

#define STAGE(BUF, KT2)                                                         \
    {                                                                           \
        int k0s = (KT2) * 64;                                                   \
        _Pragma("unroll")                                                       \
        for (int t = 0; t < 8; ++t) {                                           \
            int u = t * 8 + w;                                                  \
            int n = u & 15;                                                     \
            int hh = (u >> 4) & 1;                                              \
            if (u < 32) {                                                       \
                unsigned phys = (unsigned)n * 1024u + (unsigned)lane * 16u;     \
                unsigned key = phys >> 9;                                       \
                unsigned cl = ((phys >> 4) & 31u) ^ (key & 7u);                 \
                size_t koff = kv_base + (size_t)(k0s + hh * HB + (int)key) * DD + cl * 8; \
                gll16(kh_g + koff, &khs[BUF][hh][n * 512]);                     \
            } else {                                                            \
                unsigned dv = (unsigned)n * 16u + ((unsigned)lane >> 2);        \
                unsigned cv = ((unsigned)lane & 3u) ^ (dv & 3u) ^ ((dv >> 2) & 3u); \
                size_t voff = vt_base + (size_t)dv * LL + (unsigned)(k0s + hh * HB) + cv * 8; \
                gll16(vt_g + voff, &vts[BUF][hh][n * 512]);                     \
            }                                                                   \
        }                                                                       \
    }

    for (int ss = 0; ss < 8; ++ss) {
        int s2 = (strm0 + ss) & 7;
        for (;;) {
            __syncthreads();                       // prev item's LDS reads done
            if (tid == 0) *(int*)&khs[0][0][0] = atomicAdd(&ctr[s2], 1);
            __syncthreads();
            int it = *(const int*)&khs[0][0][0];
            __syncthreads();                       // all read it before overwrite
            if (it >= NIT_STREAM) break;
            int qt  = it & 3;
            int dir = (it >> 2) & 1;
            int b   = ((it >> 3) << 3) + s2;

            const u16 *qh_g, *kh_g, *vt_g;
            const int *qidx, *qcq, *qck;
            const float* vsp;
            float* ob;
            if (dir == 0) { qh_g=v1h; kh_g=v2h; vt_g=v2t;
                            qidx=qidx1; qcq=qcnt1; qck=qcnt2;
                            vsp = vsum + ((size_t)NB + b) * DD; ob = out; }
            else          { qh_g=v2h; kh_g=v1h; vt_g=v1t;
                            qidx=qidx2; qcq=qcnt2; qck=qcnt1;
                            vsp = vsum + (size_t)b * DD; ob = out + ELEMS; }
            int cnt_q = qcq[b];
            if (qt * BQ >= cnt_q) continue;
            int cnt_k = qck[b];
            int nkt2 = (cnt_k + 63) >> 6;

            // two q-fragments per wave: qs[qf] = qt*256 + qf*128 + w*16 + lq
            int qs0 = qt * BQ + w * 16 + lq;          // max 1023 (qt<=3)
            int qs1 = qs0 + 128;
            const u16* qb0 = qh_g + ((size_t)b * LL + qs0) * DD + g * 8;
            const u16* qb1 = qh_g + ((size_t)b * LL + qs1) * DD + g * 8;
            half8 qhf[2][8];
#pragma unroll
            for (int ks = 0; ks < 8; ++ks) {
                qhf[0][ks] = *(const half8*)(const void*)(qb0 + ks * 32);
                qhf[1][ks] = *(const half8*)(const void*)(qb1 + ks * 32);
            }

            float m[2] = {MASK_FILL, MASK_FILL};
            float z[2] = {0.f, 0.f};
            f32x4 o[2][16];
#pragma unroll
            for (int qf = 0; qf < 2; ++qf)
#pragma unroll
                for (int i2 = 0; i2 < 16; ++i2) o[qf][i2] = (f32x4){0.f, 0.f, 0.f, 0.f};

            const size_t kv_base = (size_t)b * LL * DD;
            const size_t vt_base = (size_t)b * DD * LL;

            if (nkt2 > 0) {
                int cur = 0;
                STAGE(0, 0);
                asm volatile("s_waitcnt vmcnt(0)" ::: "memory");
                __builtin_amdgcn_s_barrier();
                __builtin_amdgcn_sched_barrier(0);

                for (int kt2 = 0; kt2 < nkt2; ++kt2) {
                    int k0 = kt2 * 64;
                    if (kt2 + 1 < nkt2) STAGE(cur ^ 1, kt2 + 1);

                    // S^T = K @ Q^T: K fragments register-reused across 2 q-frags
                    f32x4 sa[2][2][2];   // [hh][rt][qf]
#pragma unroll
                    for (int hh = 0; hh < 2; ++hh)
#pragma unroll
                        for (int rt = 0; rt < 2; ++rt)
#pragma unroll
                            for (int qf = 0; qf < 2; ++qf)
                                sa[hh][rt][qf] = (f32x4){0.f, 0.f, 0.f, 0.f};
                    __builtin_amdgcn_s_setprio(1);
#pragma unroll
                    for (int hh = 0; hh < 2; ++hh) {
#pragma unroll
                        for (int ks = 0; ks < 8; ++ks) {
                            int cidx = ((ks * 4 + g) ^ (lq & 7)) * 8;
                            half8 kh0 = *(const half8*)(const void*)&khs[cur][hh][lq * 256 + cidx];
                            half8 kh1 = *(const half8*)(const void*)&khs[cur][hh][(16 + lq) * 256 + cidx];
                            sa[hh][0][0] = __builtin_amdgcn_mfma_f32_16x16x32_f16(kh0, qhf[0][ks], sa[hh][0][0], 0, 0, 0);
                            sa[hh][0][1] = __builtin_amdgcn_mfma_f32_16x16x32_f16(kh0, qhf[1][ks], sa[hh][0][1], 0, 0, 0);
                            sa[hh][1][0] = __builtin_amdgcn_mfma_f32_16x16x32_f16(kh1, qhf[0][ks], sa[hh][1][0], 0, 0, 0);
                            sa[hh][1][1] = __builtin_amdgcn_mfma_f32_16x16x32_f16(kh1, qhf[1][ks], sa[hh][1][1], 0, 0, 0);
                        }
                    }
                    __builtin_amdgcn_s_setprio(0);

                    // per-qf online softmax (T13 defer-max, exact bookkeeping)
                    union { unsigned u[4]; half8 v; } pf[2][2];  // [hh][qf]
#pragma unroll
                    for (int qf = 0; qf < 2; ++qf) {
                        float s[16];
#pragma unroll
                        for (int hh = 0; hh < 2; ++hh)
#pragma unroll
                            for (int i2 = 0; i2 < 4; ++i2) {
                                s[hh * 8 + i2]     = sa[hh][0][qf][i2];
                                s[hh * 8 + 4 + i2] = sa[hh][1][qf][i2];
                            }
                        if (kt2 == nkt2 - 1) {       // tail clamp: fake keys -> -inf
#pragma unroll
                            for (int hh = 0; hh < 2; ++hh) {
                                int base = k0 + hh * HB + 4 * g;
#pragma unroll
                                for (int i2 = 0; i2 < 4; ++i2) {
                                    if (base + i2 >= cnt_k)      s[hh * 8 + i2]     = -1e30f;
                                    if (base + 16 + i2 >= cnt_k) s[hh * 8 + 4 + i2] = -1e30f;
                                }
                            }
                        }
                        float pmax = s[0];
#pragma unroll
                        for (int i2 = 1; i2 < 16; ++i2) pmax = fmaxf(pmax, s[i2]);
                        pmax = fmaxf(pmax, __shfl_xor(pmax, 16));
                        pmax = fmaxf(pmax, __shfl_xor(pmax, 32));
                        if (__any(pmax > m[qf] + 8.f)) {   // T13: rescale only on big jump
                            float mnew = fmaxf(m[qf], pmax);
                            float alpha = __expf(m[qf] - mnew);
                            z[qf] *= alpha;
#pragma unroll
                            for (int i2 = 0; i2 < 16; ++i2) o[qf][i2] *= alpha;
                            m[qf] = mnew;
                        }
                        float p[16], psum = 0.f;
#pragma unroll
                        for (int i2 = 0; i2 < 16; ++i2) { p[i2] = __expf(s[i2] - m[qf]); psum += p[i2]; }
                        psum += __shfl_xor(psum, 16);
                        psum += __shfl_xor(psum, 32);
                        z[qf] += psum;

                        int srcA = ((lane & 16) << 1) | lq;
                        int srcB = srcA + 16;
                        bool sel = (g >> 1) != 0;
#pragma unroll
                        for (int hh = 0; hh < 2; ++hh) {
                            unsigned pk00 = pkf16(p[hh * 8 + 0], p[hh * 8 + 1]);
                            unsigned pk01 = pkf16(p[hh * 8 + 2], p[hh * 8 + 3]);
                            unsigned pk10 = pkf16(p[hh * 8 + 4], p[hh * 8 + 5]);
                            unsigned pk11 = pkf16(p[hh * 8 + 6], p[hh * 8 + 7]);
                            unsigned a00 = (unsigned)__shfl((int)pk00, srcA);
                            unsigned a01 = (unsigned)__shfl((int)pk01, srcA);
                            unsigned a10 = (unsigned)__shfl((int)pk10, srcA);
                            unsigned a11 = (unsigned)__shfl((int)pk11, srcA);
                            unsigned b00 = (unsigned)__shfl((int)pk00, srcB);
                            unsigned b01 = (unsigned)__shfl((int)pk01, srcB);
                            unsigned b10 = (unsigned)__shfl((int)pk10, srcB);
                            unsigned b11 = (unsigned)__shfl((int)pk11, srcB);
                            pf[hh][qf].u[0] = sel ? a10 : a00;
                            pf[hh][qf].u[1] = sel ? a11 : a01;
                            pf[hh][qf].u[2] = sel ? b10 : b00;
                            pf[hh][qf].u[3] = sel ? b11 : b01;
                        }
                    }

                    // O^T += V^T @ P^T: V fragments register-reused across 2 q-frags
                    __builtin_amdgcn_s_setprio(1);
#pragma unroll
                    for (int dt = 0; dt < 16; ++dt) {
                        int d = dt * 16 + lq;
                        half8 vf0 = *(const half8*)(const void*)&vts[cur][0][d * 32 + pvcc];
                        half8 vf1 = *(const half8*)(const void*)&vts[cur][1][d * 32 + pvcc];
                        o[0][dt] = __builtin_amdgcn_mfma_f32_16x16x32_f16(vf0, pf[0][0].v, o[0][dt], 0, 0, 0);
                        o[0][dt] = __builtin_amdgcn_mfma_f32_16x16x32_f16(vf1, pf[1][0].v, o[0][dt], 0, 0, 0);
                        o[1][dt] = __builtin_amdgcn_mfma_f32_16x16x32_f16(vf0, pf[0][1].v, o[1][dt], 0, 0, 0);
                        o[1][dt] = __builtin_amdgcn_mfma_f32_16x16x32_f16(vf1, pf[1][1].v, o[1][dt], 0, 0, 0);
                    }
                    __builtin_amdgcn_s_setprio(0);

                    if (kt2 + 1 < nkt2) {
                        asm volatile("s_waitcnt vmcnt(0)" ::: "memory");
                        __builtin_amdgcn_s_barrier();
                        __builtin_amdgcn_sched_barrier(0);
                    }
                    cur ^= 1;
                }
            }

            // exact masked-key lump + output (per q-fragment)
#pragma unroll
            for (int qf = 0; qf < 2; ++qf) {
                int qs = qf ? (qt * BQ + 128 + w * 16 + lq) : (qt * BQ + w * 16 + lq);
                float wl = __expf(MASK_FILL - m[qf]);   // m >= MASK_FILL always
                float zq = z[qf] + (float)(LL - cnt_k) * wl;
                if (qs < cnt_q) {
                    int qrow = qidx[b * LL + qs];
                    float zinv = 1.0f / zq;
                    float* orow = ob + ((size_t)b * LL + qrow) * DD + 4 * g;
#pragma unroll
                    for (int dt = 0; dt < 16; ++dt) {
                        f32x4 vv = *(const f32x4*)(vsp + dt * 16 + 4 * g);
                        f32x4 ov = (o[qf][dt] + wl * vv) * zinv;
                        *(f32x4*)(orow + dt * 16) = ov;
                    }
                }
            }
        }
    }
#undef STAGE
}

extern "C" void kernel_launch(void* const* d_in, const int* in_sizes, int n_in,
                              void* d_out, int out_size, void* d_ws, size_t ws_size,
                              hipStream_t stream)
{
    const float* v1      = (const float*)d_in[0];
    const void*  v1_mask = d_in[1];
    const float* v2      = (const float*)d_in[2];
    const void*  v2_mask = d_in[3];
    float* out = (float*)d_out;

    u16* v1h = (u16*)d_ws;           // compacted fp16 (row = compact slot)
    u16* v2h = v1h + ELEMS;
    u16* v1t = v2h + ELEMS;          // compacted fp16 transpose [b][d][slot]
    u16* v2t = v1t + ELEMS;
    int* qidx1 = (int*)(v2t + ELEMS);
    int* qcnt1 = qidx1 + NB * LL;
    int* qidx2 = qcnt1 + NB;
    int* qcnt2 = qidx2 + NB * LL;
    int* cm1   = qcnt2 + NB;
    int* cm2   = cm1 + NB * LL;
    int* pa1   = cm2 + NB * LL;
    int* pa2   = pa1 + NB * LL;
    int* ctr   = pa2 + NB * LL;                  // [8] steal counters
    float* part = (float*)(ctr + 16);            // [2][NB][16][256]
    float* vsum = part + 2 * NB * 16 * 256;      // [2][NB][256]

    prep_masks<<<dim3(128), dim3(256), 0, stream>>>(
        v1_mask, v2_mask, cm1, cm2,
        qidx1, pa1, qcnt1, qidx2, pa2, qcnt2, ctr);

    prep2_kernel<<<dim3(2 * NB * 64), dim3(256), 0, stream>>>(
        v1, v1h, v1t, cm1, pa1, qidx1, qcnt1,
        v2, v2h, v2t, cm2, pa2, qidx2, qcnt2, part, out);
    vsum_reduce<<<dim3(2 * NB), dim3(256), 0, stream>>>(part, vsum);

    // persistent, work-stealing fused flash (BQ=256, 1 block/CU, 128KB LDS)
    flash_fused<<<dim3(256), dim3(512), 0, stream>>>(
        v1h, v2h, v1t, v2t,
        qidx1, qcnt1, qidx2, qcnt2, vsum, ctr, out);
}

// Round 15
// 209.234 us; speedup vs baseline: 1.2562x; 1.2562x over previous
//
#include <hip/hip_runtime.h>
#include <hip/hip_bf16.h>
#include <hip/hip_fp16.h>
#include <stdint.h>

// BidirectionalAttention2: two flash-attention passes over sim = v1 @ v2^T.
// R15: revert R14 (BQ=256 spilled: VGPR capped 128, WRITE 65->100MB, flash
//      174us). Base = R12 (session best, flash 122us). Single added lever:
//      T13 defer-max (THR=8, exact): rescale o/z only when pmax > m+8.
//      P <= e^8 (fp16-safe), z and masked-key lump share m's scale -> exact.
//      Kept: fp16 single-pass QK, BQ=128, 64-key double-buffered steps,
//      exact masked-key lump, compacted K/V, per-XCD work steal, setprio,
//      vectorized prep transpose, vf-preload.

#define MASK_FILL -1e-07f

typedef unsigned short u16;
typedef _Float16 half8 __attribute__((ext_vector_type(8)));
typedef __attribute__((ext_vector_type(4))) float f32x4;
typedef __attribute__((ext_vector_type(4))) u16 u16x4;

#define NB 64
#define LL 1024
#define DD 256
#define BQ 128
#define HB 32                 // half-block of keys (sub-tile)
#define ELEMS ((size_t)NB * LL * DD)
#define NIT_STREAM 128        // items per stream: qt(8) x dir(2) x boct(8)

__device__ __forceinline__ u16 f16b(float f) {
    _Float16 h = (_Float16)f;
    return __builtin_bit_cast(u16, h);
}
__device__ __forceinline__ unsigned pkf16(float a, float b) {
    return (unsigned)f16b(a) | ((unsigned)f16b(b) << 16);
}

__device__ __forceinline__ void gll16(const u16* g, u16* l) {
    __builtin_amdgcn_global_load_lds(
        (const __attribute__((address_space(1))) void*)g,
        (__attribute__((address_space(3))) void*)l, 16, 0, 0);
}

// ---- fused: mask dtype detect + convert + per-batch compaction + ctr clear --
__global__ __launch_bounds__(256) void prep_masks(
    const void* __restrict__ m1, const void* __restrict__ m2,
    int* __restrict__ cm1, int* __restrict__ cm2,
    int* __restrict__ qidx1, int* __restrict__ pa1, int* __restrict__ qcnt1,
    int* __restrict__ qidx2, int* __restrict__ pa2, int* __restrict__ qcnt2,
    int* __restrict__ ctr)
{
    int blk = blockIdx.x, tid = threadIdx.x;
    int msk = blk >> 6, b = blk & 63;
    const unsigned* w1 = (const unsigned*)m1;
    const unsigned* w2 = (const unsigned*)m2;
    unsigned acc = 0;
    for (int i = tid; i < 4096; i += 256) acc |= (w1[i] | w2[i]) & ~1u;
    __shared__ unsigned red[256];
    red[tid] = acc;
    __syncthreads();
    for (int o = 128; o; o >>= 1) {
        if (tid < o) red[tid] |= red[tid + o];
        __syncthreads();
    }
    int isbool = red[0] ? 1 : 0;

    const void* m = msk ? m2 : m1;
    int* cm   = msk ? cm2 : cm1;
    int* qidx = msk ? qidx2 : qidx1;
    int* pa   = msk ? pa2 : pa1;
    int* qcnt = msk ? qcnt2 : qcnt1;

    __shared__ int ps[256];
    int f[4], s = 0;
#pragma unroll
    for (int j = 0; j < 4; ++j) {
        int idx = b * LL + tid * 4 + j;
        int v = isbool ? (int)((const unsigned char*)m)[idx] : ((const int*)m)[idx];
        cm[idx] = v ? 1 : 0;
        f[j] = (v == 0) ? 1 : 0;
        s += f[j];
    }
    ps[tid] = s;
    __syncthreads();
    for (int off = 1; off < 256; off <<= 1) {
        int v = (tid >= off) ? ps[tid - off] : 0;
        __syncthreads();
        ps[tid] += v;
        __syncthreads();
    }
    int pos = (tid > 0) ? ps[tid - 1] : 0;
#pragma unroll
    for (int j = 0; j < 4; ++j) {
        pa[b * LL + tid * 4 + j] = pos;
        if (f[j]) qidx[b * LL + (pos++)] = tid * 4 + j;
    }
    if (tid == 255) qcnt[b] = ps[255];
    if (blk == 0 && tid < 8) ctr[tid] = 0;
}

// ---- prep: fp32 -> fp16 COMPACTED rows + compacted fp16 transpose +
// ---- masked-V partial sums + zeroing of masked output rows (fused) ----------
__global__ __launch_bounds__(256) void prep2_kernel(
    const float* __restrict__ x1, u16* __restrict__ h1, u16* __restrict__ t1,
    const int* __restrict__ cm1, const int* __restrict__ pa1,
    const int* __restrict__ qi1, const int* __restrict__ qc1,
    const float* __restrict__ x2, u16* __restrict__ h2, u16* __restrict__ t2,
    const int* __restrict__ cm2, const int* __restrict__ pa2,
    const int* __restrict__ qi2, const int* __restrict__ qc2,
    float* __restrict__ part, float* __restrict__ out)
{
    __shared__ u16 t[64][65];
    __shared__ float ps2[16][68];
    int blk = blockIdx.x;
    int tensor = blk >> 12;
    blk &= 4095;
    const float* x = tensor ? x2 : x1;
    u16* h  = tensor ? h2 : h1;
    u16* xt = tensor ? t2 : t1;
    const int* cm = tensor ? cm2 : cm1;
    const int* pa = tensor ? pa2 : pa1;
    const int* qi = tensor ? qi2 : qi1;
    const int* qc = tensor ? qc2 : qc1;
    float* outb = out + (tensor ? ELEMS : 0);
    int b = blk >> 6, lt = (blk >> 2) & 15, dt = blk & 3;
    int l0 = lt * 64, d0 = dt * 64;
    int tid = threadIdx.x;
    int sub = tid >> 4;
    int c16 = tid & 15;
    float vpart[4] = {0.f, 0.f, 0.f, 0.f};
#pragma unroll
    for (int p = 0; p < 4; ++p) {
        int row = p * 16 + sub;
        int l = l0 + row;
        int masked = cm[b * LL + l];
        int slot = pa[b * LL + l];
        f32x4 v = *(const f32x4*)(x + ((size_t)b * LL + l) * DD + d0 + c16 * 4);
        u16x4 hv;
#pragma unroll
        for (int e = 0; e < 4; ++e) {
            hv[e] = f16b(v[e]);
            t[c16 * 4 + e][row] = hv[e];
            if (masked) vpart[e] += v[e];
        }
        if (!masked) {
            *(u16x4*)(h + ((size_t)b * LL + slot) * DD + d0 + c16 * 4) = hv;
        } else {
            f32x4 z4 = {0.f, 0.f, 0.f, 0.f};
            *(f32x4*)(outb + ((size_t)b * LL + l) * DD + d0 + c16 * 4) = z4;
        }
    }
#pragma unroll
    for (int e = 0; e < 4; ++e) ps2[sub][c16 * 4 + e] = vpart[e];
    __syncthreads();
    // compacted transpose, slot-aligned u16x4 stores (head/tail scalar)
    int first = pa[b * LL + l0];
    int cntb = qc[b];
    int nun = ((lt == 15) ? cntb : pa[b * LL + l0 + 64]) - first;
    int last = first + nun;
    int q0 = first >> 2;
    int nq = ((last + 3) >> 2) - q0;     // <= 17 aligned quads
    const int* qib = qi + b * LL;
#pragma unroll
    for (int p = 0; p < 4; ++p) {
        int d = p * 16 + sub;
        u16* xrow = xt + ((size_t)b * DD + d0 + d) * LL;
        for (int qq = c16; qq < nq; qq += 16) {
            int s0 = (q0 + qq) << 2;
            if (s0 >= first && s0 + 4 <= last) {
                u16x4 ov;
#pragma unroll
                for (int e = 0; e < 4; ++e) {
                    int col = qib[s0 + e] - l0;
                    ov[e] = t[d][col];
                }
                *(u16x4*)(xrow + s0) = ov;
            } else {
#pragma unroll
                for (int e = 0; e < 4; ++e) {
                    int sl = s0 + e;
                    if (sl >= first && sl < last) {
                        int col = qib[sl] - l0;
                        xrow[sl] = t[d][col];
                    }
                }
            }
        }
    }
    if (tid < 64) {
        float s = 0.f;
#pragma unroll
        for (int k = 0; k < 16; ++k) s += ps2[k][tid];
        part[(((size_t)tensor * NB + b) * 16 + lt) * 256 + d0 + tid] = s;
    }
}

// ---- reduce per-tile partials -> Vsum[tensor][b][256] (fixed order) ---------
__global__ __launch_bounds__(256) void vsum_reduce(
    const float* __restrict__ part, float* __restrict__ vsum)
{
    int blk = blockIdx.x;       // tensor*NB + b
    int d = threadIdx.x;
    float s = 0.f;
#pragma unroll
    for (int lt = 0; lt < 16; ++lt)
        s += part[((size_t)blk * 16 + lt) * 256 + d];
    vsum[(size_t)blk * DD + d] = s;
}

// ---- persistent fused flash: fp16 1-pass QK, 64 keys/barrier, 128KB LDS -----
// 256 blocks x 512 thr (1/CU). stream = blockIdx&7 -> batches b%8.
__global__ __launch_bounds__(512, 2) void flash_fused(
    const u16* __restrict__ v1h, const u16* __restrict__ v2h,
    const u16* __restrict__ v1t, const u16* __restrict__ v2t,
    const int* __restrict__ qidx1, const int* __restrict__ qcnt1,
    const int* __restrict__ qidx2, const int* __restrict__ qcnt2,
    const float* __restrict__ vsum, int* __restrict__ ctr,
    float* __restrict__ out)
{
    int strm0 = blockIdx.x & 7;
    int tid = threadIdx.x;
    int w = tid >> 6, lane = tid & 63;
    int lq = lane & 15, g = lane >> 4;

    __shared__ __align__(16) u16 khs[2][2][HB * DD];  // [key][d], chunk ^ (key&7)
    __shared__ __align__(16) u16 vts[2][2][HB * DD];  // [d][key], chunk ^ (d&3)^((d>>2)&3)

    const int pvcc = (g ^ (lq & 3) ^ ((lq >> 2) & 3)) * 8;

#define STAGE(BUF, KT2)                                                         \
    {                                                                           \
        int k0s = (KT2) * 64;                                                   \
        _Pragma("unroll")                                                       \
        for (int t = 0; t < 8; ++t) {                                           \
            int u = t * 8 + w;                                                  \
            int n = u & 15;                                                     \
            int hh = (u >> 4) & 1;                                              \
            if (u < 32) {                                                       \
                unsigned phys = (unsigned)n * 1024u + (unsigned)lane * 16u;     \
                unsigned key = phys >> 9;                                       \
                unsigned cl = ((phys >> 4) & 31u) ^ (key & 7u);                 \
                size_t koff = kv_base + (size_t)(k0s + hh * HB + (int)key) * DD + cl * 8; \
                gll16(kh_g + koff, &khs[BUF][hh][n * 512]);                     \
            } else {                                                            \
                unsigned dv = (unsigned)n * 16u + ((unsigned)lane >> 2);        \
                unsigned cv = ((unsigned)lane & 3u) ^ (dv & 3u) ^ ((dv >> 2) & 3u); \
                size_t voff = vt_base + (size_t)dv * LL + (unsigned)(k0s + hh * HB) + cv * 8; \
                gll16(vt_g + voff, &vts[BUF][hh][n * 512]);                     \
            }                                                                   \
        }                                                                       \
    }

    for (int ss = 0; ss < 8; ++ss) {
        int s2 = (strm0 + ss) & 7;
        for (;;) {
            __syncthreads();                       // prev item's LDS reads done
            if (tid == 0) *(int*)&khs[0][0][0] = atomicAdd(&ctr[s2], 1);
            __syncthreads();
            int it = *(const int*)&khs[0][0][0];
            __syncthreads();                       // all read it before overwrite
            if (it >= NIT_STREAM) break;
            int qt  = it & 7;
            int dir = (it >> 3) & 1;
            int b   = ((it >> 4) << 3) + s2;

            const u16 *qh_g, *kh_g, *vt_g;
            const int *qidx, *qcq, *qck;
            const float* vsp;
            float* ob;
            if (dir == 0) { qh_g=v1h; kh_g=v2h; vt_g=v2t;
                            qidx=qidx1; qcq=qcnt1; qck=qcnt2;
                            vsp = vsum + ((size_t)NB + b) * DD; ob = out; }
            else          { qh_g=v2h; kh_g=v1h; vt_g=v1t;
                            qidx=qidx2; qcq=qcnt2; qck=qcnt1;
                            vsp = vsum + (size_t)b * DD; ob = out + ELEMS; }
            int cnt_q = qcq[b];
            if (qt * BQ >= cnt_q) continue;
            int cnt_k = qck[b];
            int nkt2 = (cnt_k + 63) >> 6;

            int qslot = qt * BQ + w * 16 + lq;
            bool qvalid = qslot < cnt_q;

            const u16* qbh = qh_g + ((size_t)b * LL + qslot) * DD + g * 8;
            half8 qhf[8];
#pragma unroll
            for (int ks = 0; ks < 8; ++ks)
                qhf[ks] = *(const half8*)(const void*)(qbh + ks * 32);

            float m = MASK_FILL, z = 0.f;
            f32x4 o[16];
#pragma unroll
            for (int i2 = 0; i2 < 16; ++i2) o[i2] = (f32x4){0.f, 0.f, 0.f, 0.f};

            const size_t kv_base = (size_t)b * LL * DD;
            const size_t vt_base = (size_t)b * DD * LL;

            if (nkt2 > 0) {
                int cur = 0;
                STAGE(0, 0);
                asm volatile("s_waitcnt vmcnt(0)" ::: "memory");
                __builtin_amdgcn_s_barrier();
                __builtin_amdgcn_sched_barrier(0);

                for (int kt2 = 0; kt2 < nkt2; ++kt2) {
                    int k0 = kt2 * 64;
                    if (kt2 + 1 < nkt2) STAGE(cur ^ 1, kt2 + 1);

                    // S^T = K @ Q^T over 64 keys (2 halves x 2 row-tiles)
                    f32x4 sa[2][2];
#pragma unroll
                    for (int hh = 0; hh < 2; ++hh)
#pragma unroll
                        for (int rt = 0; rt < 2; ++rt)
                            sa[hh][rt] = (f32x4){0.f, 0.f, 0.f, 0.f};
                    __builtin_amdgcn_s_setprio(1);
#pragma unroll
                    for (int hh = 0; hh < 2; ++hh) {
#pragma unroll
                        for (int ks = 0; ks < 8; ++ks) {
                            int cidx = ((ks * 4 + g) ^ (lq & 7)) * 8;
                            half8 kh0 = *(const half8*)(const void*)&khs[cur][hh][lq * 256 + cidx];
                            half8 kh1 = *(const half8*)(const void*)&khs[cur][hh][(16 + lq) * 256 + cidx];
                            sa[hh][0] = __builtin_amdgcn_mfma_f32_16x16x32_f16(kh0, qhf[ks], sa[hh][0], 0, 0, 0);
                            sa[hh][1] = __builtin_amdgcn_mfma_f32_16x16x32_f16(kh1, qhf[ks], sa[hh][1], 0, 0, 0);
                        }
                    }
                    __builtin_amdgcn_s_setprio(0);

                    // preload PV A-fragments for dt=0..7 (latency under softmax)
                    half8 vfA[8], vfB[8];
#pragma unroll
                    for (int dt = 0; dt < 8; ++dt) {
                        int d = dt * 16 + lq;
                        vfA[dt] = *(const half8*)(const void*)&vts[cur][0][d * 32 + pvcc];
                        vfB[dt] = *(const half8*)(const void*)&vts[cur][1][d * 32 + pvcc];
                    }

                    float s[16];
#pragma unroll
                    for (int hh = 0; hh < 2; ++hh)
#pragma unroll
                        for (int i2 = 0; i2 < 4; ++i2) {
                            s[hh * 8 + i2]     = sa[hh][0][i2];
                            s[hh * 8 + 4 + i2] = sa[hh][1][i2];
                        }
                    if (kt2 == nkt2 - 1) {           // tail clamp: fake keys -> -inf
#pragma unroll
                        for (int hh = 0; hh < 2; ++hh) {
                            int base = k0 + hh * HB + 4 * g;
#pragma unroll
                            for (int i2 = 0; i2 < 4; ++i2) {
                                if (base + i2 >= cnt_k)      s[hh * 8 + i2]     = -1e30f;
                                if (base + 16 + i2 >= cnt_k) s[hh * 8 + 4 + i2] = -1e30f;
                            }
                        }
                    }
                    float pmax = s[0];
#pragma unroll
                    for (int i2 = 1; i2 < 16; ++i2) pmax = fmaxf(pmax, s[i2]);
                    pmax = fmaxf(pmax, __shfl_xor(pmax, 16));
                    pmax = fmaxf(pmax, __shfl_xor(pmax, 32));
                    if (__any(pmax > m + 8.f)) {     // T13 defer-max (exact)
                        float mnew = fmaxf(m, pmax);
                        float alpha = __expf(m - mnew);
                        z *= alpha;
#pragma unroll
                        for (int i2 = 0; i2 < 16; ++i2) o[i2] *= alpha;
                        m = mnew;
                    }
                    float p[16], psum = 0.f;
#pragma unroll
                    for (int i2 = 0; i2 < 16; ++i2) { p[i2] = __expf(s[i2] - m); psum += p[i2]; }
                    psum += __shfl_xor(psum, 16);
                    psum += __shfl_xor(psum, 32);
                    z += psum;

                    // P -> PV B-fragments (one per half), in-register exchange
                    union { unsigned u[4]; half8 v; } pf[2];
                    int srcA = ((lane & 16) << 1) | lq;
                    int srcB = srcA + 16;
                    bool sel = (g >> 1) != 0;
#pragma unroll
                    for (int hh = 0; hh < 2; ++hh) {
                        unsigned pk00 = pkf16(p[hh * 8 + 0], p[hh * 8 + 1]);
                        unsigned pk01 = pkf16(p[hh * 8 + 2], p[hh * 8 + 3]);
                        unsigned pk10 = pkf16(p[hh * 8 + 4], p[hh * 8 + 5]);
                        unsigned pk11 = pkf16(p[hh * 8 + 6], p[hh * 8 + 7]);
                        unsigned a00 = (unsigned)__shfl((int)pk00, srcA);
                        unsigned a01 = (unsigned)__shfl((int)pk01, srcA);
                        unsigned a10 = (unsigned)__shfl((int)pk10, srcA);
                        unsigned a11 = (unsigned)__shfl((int)pk11, srcA);
                        unsigned b00 = (unsigned)__shfl((int)pk00, srcB);
                        unsigned b01 = (unsigned)__shfl((int)pk01, srcB);
                        unsigned b10 = (unsigned)__shfl((int)pk10, srcB);
                        unsigned b11 = (unsigned)__shfl((int)pk11, srcB);
                        pf[hh].u[0] = sel ? a10 : a00;
                        pf[hh].u[1] = sel ? a11 : a01;
                        pf[hh].u[2] = sel ? b10 : b00;
                        pf[hh].u[3] = sel ? b11 : b01;
                    }

                    // O^T += V^T @ P^T: dt 0..7 from preloaded regs, 8..15 inline
                    __builtin_amdgcn_s_setprio(1);
#pragma unroll
                    for (int dt = 0; dt < 8; ++dt) {
                        o[dt] = __builtin_amdgcn_mfma_f32_16x16x32_f16(vfA[dt], pf[0].v, o[dt], 0, 0, 0);
                        o[dt] = __builtin_amdgcn_mfma_f32_16x16x32_f16(vfB[dt], pf[1].v, o[dt], 0, 0, 0);
                    }
#pragma unroll
                    for (int dt = 8; dt < 16; ++dt) {
                        int d = dt * 16 + lq;
                        half8 vf0 = *(const half8*)(const void*)&vts[cur][0][d * 32 + pvcc];
                        half8 vf1 = *(const half8*)(const void*)&vts[cur][1][d * 32 + pvcc];
                        o[dt] = __builtin_amdgcn_mfma_f32_16x16x32_f16(vf0, pf[0].v, o[dt], 0, 0, 0);
                        o[dt] = __builtin_amdgcn_mfma_f32_16x16x32_f16(vf1, pf[1].v, o[dt], 0, 0, 0);
                    }
                    __builtin_amdgcn_s_setprio(0);

                    if (kt2 + 1 < nkt2) {
                        asm volatile("s_waitcnt vmcnt(0)" ::: "memory");
                        __builtin_amdgcn_s_barrier();
                        __builtin_amdgcn_sched_barrier(0);
                    }
                    cur ^= 1;
                }
            }

            // exact masked-key lump: all masked logits == MASK_FILL
            float wl = __expf(MASK_FILL - m);      // m >= MASK_FILL always
            z += (float)(LL - cnt_k) * wl;
#pragma unroll
            for (int dt = 0; dt < 16; ++dt) {
                f32x4 vv = *(const f32x4*)(vsp + dt * 16 + 4 * g);
                o[dt] += wl * vv;
            }

            if (qvalid) {
                int qrow = qidx[b * LL + qslot];
                float zinv = 1.0f / z;
                float* orow = ob + ((size_t)b * LL + qrow) * DD + 4 * g;
#pragma unroll
                for (int dt = 0; dt < 16; ++dt) {
                    f32x4 vv = o[dt] * zinv;
                    *(f32x4*)(orow + dt * 16) = vv;
                }
            }
        }
    }
#undef STAGE
}

extern "C" void kernel_launch(void* const* d_in, const int* in_sizes, int n_in,
                              void* d_out, int out_size, void* d_ws, size_t ws_size,
                              hipStream_t stream)
{
    const float* v1      = (const float*)d_in[0];
    const void*  v1_mask = d_in[1];
    const float* v2      = (const float*)d_in[2];
    const void*  v2_mask = d_in[3];
    float* out = (float*)d_out;

    u16* v1h = (u16*)d_ws;           // compacted fp16 (row = compact slot)
    u16* v2h = v1h + ELEMS;
    u16* v1t = v2h + ELEMS;          // compacted fp16 transpose [b][d][slot]
    u16* v2t = v1t + ELEMS;
    int* qidx1 = (int*)(v2t + ELEMS);
    int* qcnt1 = qidx1 + NB * LL;
    int* qidx2 = qcnt1 + NB;
    int* qcnt2 = qidx2 + NB * LL;
    int* cm1   = qcnt2 + NB;
    int* cm2   = cm1 + NB * LL;
    int* pa1   = cm2 + NB * LL;
    int* pa2   = pa1 + NB * LL;
    int* ctr   = pa2 + NB * LL;                  // [8] steal counters
    float* part = (float*)(ctr + 16);            // [2][NB][16][256]
    float* vsum = part + 2 * NB * 16 * 256;      // [2][NB][256]

    prep_masks<<<dim3(128), dim3(256), 0, stream>>>(
        v1_mask, v2_mask, cm1, cm2,
        qidx1, pa1, qcnt1, qidx2, pa2, qcnt2, ctr);

    prep2_kernel<<<dim3(2 * NB * 64), dim3(256), 0, stream>>>(
        v1, v1h, v1t, cm1, pa1, qidx1, qcnt1,
        v2, v2h, v2t, cm2, pa2, qidx2, qcnt2, part, out);
    vsum_reduce<<<dim3(2 * NB), dim3(256), 0, stream>>>(part, vsum);

    // persistent, work-stealing fused flash (1 block/CU, 128KB LDS)
    flash_fused<<<dim3(256), dim3(512), 0, stream>>>(
        v1h, v2h, v1t, v2t,
        qidx1, qcnt1, qidx2, qcnt2, vsum, ctr, out);
}

// Round 16
// 188.782 us; speedup vs baseline: 1.3923x; 1.1083x over previous
//
#include <hip/hip_runtime.h>
#include <hip/hip_bf16.h>
#include <hip/hip_fp16.h>
#include <stdint.h>

// BidirectionalAttention2: two flash-attention passes over sim = v1 @ v2^T.
// R16: flash untouched (R12/R15 local optimum, 122us). prep2 transpose
//      reworked: compaction applied at LDS-WRITE time (t[d][slot-base4],
//      masked rows skip the write) so the READ side is regular vectorized
//      u16x4 at t[d][qq*4] (8B-aligned via base4=first&~3; t padded [64][72];
//      bank-audit: 4 lanes/class, conflict-free). Removes the 16 scalar
//      qib[] global gathers + 16 scalar LDS reads per thread that made
//      prep2 issue-bound. Kept: fp16 single-pass QK flash, defer-max,
//      masked-key lump, compacted K/V, work steal, setprio.

#define MASK_FILL -1e-07f

typedef unsigned short u16;
typedef _Float16 half8 __attribute__((ext_vector_type(8)));
typedef __attribute__((ext_vector_type(4))) float f32x4;
typedef __attribute__((ext_vector_type(4))) u16 u16x4;

#define NB 64
#define LL 1024
#define DD 256
#define BQ 128
#define HB 32                 // half-block of keys (sub-tile)
#define ELEMS ((size_t)NB * LL * DD)
#define NIT_STREAM 128        // items per stream: qt(8) x dir(2) x boct(8)

__device__ __forceinline__ u16 f16b(float f) {
    _Float16 h = (_Float16)f;
    return __builtin_bit_cast(u16, h);
}
__device__ __forceinline__ unsigned pkf16(float a, float b) {
    return (unsigned)f16b(a) | ((unsigned)f16b(b) << 16);
}

__device__ __forceinline__ void gll16(const u16* g, u16* l) {
    __builtin_amdgcn_global_load_lds(
        (const __attribute__((address_space(1))) void*)g,
        (__attribute__((address_space(3))) void*)l, 16, 0, 0);
}

// ---- fused: mask dtype detect + convert + per-batch compaction + ctr clear --
__global__ __launch_bounds__(256) void prep_masks(
    const void* __restrict__ m1, const void* __restrict__ m2,
    int* __restrict__ cm1, int* __restrict__ cm2,
    int* __restrict__ qidx1, int* __restrict__ pa1, int* __restrict__ qcnt1,
    int* __restrict__ qidx2, int* __restrict__ pa2, int* __restrict__ qcnt2,
    int* __restrict__ ctr)
{
    int blk = blockIdx.x, tid = threadIdx.x;
    int msk = blk >> 6, b = blk & 63;
    const unsigned* w1 = (const unsigned*)m1;
    const unsigned* w2 = (const unsigned*)m2;
    unsigned acc = 0;
    for (int i = tid; i < 4096; i += 256) acc |= (w1[i] | w2[i]) & ~1u;
    __shared__ unsigned red[256];
    red[tid] = acc;
    __syncthreads();
    for (int o = 128; o; o >>= 1) {
        if (tid < o) red[tid] |= red[tid + o];
        __syncthreads();
    }
    int isbool = red[0] ? 1 : 0;

    const void* m = msk ? m2 : m1;
    int* cm   = msk ? cm2 : cm1;
    int* qidx = msk ? qidx2 : qidx1;
    int* pa   = msk ? pa2 : pa1;
    int* qcnt = msk ? qcnt2 : qcnt1;

    __shared__ int ps[256];
    int f[4], s = 0;
#pragma unroll
    for (int j = 0; j < 4; ++j) {
        int idx = b * LL + tid * 4 + j;
        int v = isbool ? (int)((const unsigned char*)m)[idx] : ((const int*)m)[idx];
        cm[idx] = v ? 1 : 0;
        f[j] = (v == 0) ? 1 : 0;
        s += f[j];
    }
    ps[tid] = s;
    __syncthreads();
    for (int off = 1; off < 256; off <<= 1) {
        int v = (tid >= off) ? ps[tid - off] : 0;
        __syncthreads();
        ps[tid] += v;
        __syncthreads();
    }
    int pos = (tid > 0) ? ps[tid - 1] : 0;
#pragma unroll
    for (int j = 0; j < 4; ++j) {
        pa[b * LL + tid * 4 + j] = pos;
        if (f[j]) qidx[b * LL + (pos++)] = tid * 4 + j;
    }
    if (tid == 255) qcnt[b] = ps[255];
    if (blk == 0 && tid < 8) ctr[tid] = 0;
}

// ---- prep: fp32 -> fp16 COMPACTED rows + compacted fp16 transpose (write-
// ---- side compaction) + masked-V partial sums + masked-row output zeroing ---
__global__ __launch_bounds__(256) void prep2_kernel(
    const float* __restrict__ x1, u16* __restrict__ h1, u16* __restrict__ t1,
    const int* __restrict__ cm1, const int* __restrict__ pa1,
    const int* __restrict__ qc1,
    const float* __restrict__ x2, u16* __restrict__ h2, u16* __restrict__ t2,
    const int* __restrict__ cm2, const int* __restrict__ pa2,
    const int* __restrict__ qc2,
    float* __restrict__ part, float* __restrict__ out)
{
    __shared__ u16 t[64][72];          // [d][col'], col' = slot - base4, pad 72
    __shared__ float ps2[16][68];
    int blk = blockIdx.x;
    int tensor = blk >> 12;
    blk &= 4095;
    const float* x = tensor ? x2 : x1;
    u16* h  = tensor ? h2 : h1;
    u16* xt = tensor ? t2 : t1;
    const int* cm = tensor ? cm2 : cm1;
    const int* pa = tensor ? pa2 : pa1;
    const int* qc = tensor ? qc2 : qc1;
    float* outb = out + (tensor ? ELEMS : 0);
    int b = blk >> 6, lt = (blk >> 2) & 15, dt = blk & 3;
    int l0 = lt * 64, d0 = dt * 64;
    int tid = threadIdx.x;
    int sub = tid >> 4;
    int c16 = tid & 15;

    int first = pa[b * LL + l0];       // uniform across block
    int base4 = first & ~3;            // 4-aligned origin for col'

    float vpart[4] = {0.f, 0.f, 0.f, 0.f};
#pragma unroll
    for (int p = 0; p < 4; ++p) {
        int row = p * 16 + sub;
        int l = l0 + row;
        int masked = cm[b * LL + l];
        int slot = pa[b * LL + l];
        f32x4 v = *(const f32x4*)(x + ((size_t)b * LL + l) * DD + d0 + c16 * 4);
        u16x4 hv;
#pragma unroll
        for (int e = 0; e < 4; ++e) {
            hv[e] = f16b(v[e]);
            if (masked) vpart[e] += v[e];
        }
        if (!masked) {
            int colp = slot - base4;   // 0..66
#pragma unroll
            for (int e = 0; e < 4; ++e) t[c16 * 4 + e][colp] = hv[e];
            *(u16x4*)(h + ((size_t)b * LL + slot) * DD + d0 + c16 * 4) = hv;
        } else {
            f32x4 z4 = {0.f, 0.f, 0.f, 0.f};
            *(f32x4*)(outb + ((size_t)b * LL + l) * DD + d0 + c16 * 4) = z4;
        }
    }
#pragma unroll
    for (int e = 0; e < 4; ++e) ps2[sub][c16 * 4 + e] = vpart[e];
    __syncthreads();
    // transpose flush: vectorized u16x4 reads at t[d][qq*4] (8B-aligned)
    int cntb = qc[b];
    int nun = ((lt == 15) ? cntb : pa[b * LL + l0 + 64]) - first;
    int last = first + nun;
    int q0 = first >> 2;
    int nq = ((last + 3) >> 2) - q0;     // <= 17 aligned quads
#pragma unroll
    for (int p = 0; p < 4; ++p) {
        int d = p * 16 + sub;
        u16* xrow = xt + ((size_t)b * DD + d0 + d) * LL;
        for (int qq = c16; qq < nq; qq += 16) {
            int s0 = (q0 + qq) << 2;           // absolute slot of quad start
            if (s0 >= first && s0 + 4 <= last) {
                u16x4 ov = *(const u16x4*)&t[d][qq * 4];
                *(u16x4*)(xrow + s0) = ov;
            } else {
#pragma unroll
                for (int e = 0; e < 4; ++e) {
                    int sl = s0 + e;
                    if (sl >= first && sl < last)
                        xrow[sl] = t[d][sl - base4];
                }
            }
        }
    }
    if (tid < 64) {
        float s = 0.f;
#pragma unroll
        for (int k = 0; k < 16; ++k) s += ps2[k][tid];
        part[(((size_t)tensor * NB + b) * 16 + lt) * 256 + d0 + tid] = s;
    }
}

// ---- reduce per-tile partials -> Vsum[tensor][b][256] (fixed order) ---------
__global__ __launch_bounds__(256) void vsum_reduce(
    const float* __restrict__ part, float* __restrict__ vsum)
{
    int blk = blockIdx.x;       // tensor*NB + b
    int d = threadIdx.x;
    float s = 0.f;
#pragma unroll
    for (int lt = 0; lt < 16; ++lt)
        s += part[((size_t)blk * 16 + lt) * 256 + d];
    vsum[(size_t)blk * DD + d] = s;
}

// ---- persistent fused flash: fp16 1-pass QK, 64 keys/barrier, 128KB LDS -----
// 256 blocks x 512 thr (1/CU). stream = blockIdx&7 -> batches b%8.
__global__ __launch_bounds__(512, 2) void flash_fused(
    const u16* __restrict__ v1h, const u16* __restrict__ v2h,
    const u16* __restrict__ v1t, const u16* __restrict__ v2t,
    const int* __restrict__ qidx1, const int* __restrict__ qcnt1,
    const int* __restrict__ qidx2, const int* __restrict__ qcnt2,
    const float* __restrict__ vsum, int* __restrict__ ctr,
    float* __restrict__ out)
{
    int strm0 = blockIdx.x & 7;
    int tid = threadIdx.x;
    int w = tid >> 6, lane = tid & 63;
    int lq = lane & 15, g = lane >> 4;

    __shared__ __align__(16) u16 khs[2][2][HB * DD];  // [key][d], chunk ^ (key&7)
    __shared__ __align__(16) u16 vts[2][2][HB * DD];  // [d][key], chunk ^ (d&3)^((d>>2)&3)

    const int pvcc = (g ^ (lq & 3) ^ ((lq >> 2) & 3)) * 8;

#define STAGE(BUF, KT2)                                                         \
    {                                                                           \
        int k0s = (KT2) * 64;                                                   \
        _Pragma("unroll")                                                       \
        for (int t = 0; t < 8; ++t) {                                           \
            int u = t * 8 + w;                                                  \
            int n = u & 15;                                                     \
            int hh = (u >> 4) & 1;                                              \
            if (u < 32) {                                                       \
                unsigned phys = (unsigned)n * 1024u + (unsigned)lane * 16u;     \
                unsigned key = phys >> 9;                                       \
                unsigned cl = ((phys >> 4) & 31u) ^ (key & 7u);                 \
                size_t koff = kv_base + (size_t)(k0s + hh * HB + (int)key) * DD + cl * 8; \
                gll16(kh_g + koff, &khs[BUF][hh][n * 512]);                     \
            } else {                                                            \
                unsigned dv = (unsigned)n * 16u + ((unsigned)lane >> 2);        \
                unsigned cv = ((unsigned)lane & 3u) ^ (dv & 3u) ^ ((dv >> 2) & 3u); \
                size_t voff = vt_base + (size_t)dv * LL + (unsigned)(k0s + hh * HB) + cv * 8; \
                gll16(vt_g + voff, &vts[BUF][hh][n * 512]);                     \
            }                                                                   \
        }                                                                       \
    }

    for (int ss = 0; ss < 8; ++ss) {
        int s2 = (strm0 + ss) & 7;
        for (;;) {
            __syncthreads();                       // prev item's LDS reads done
            if (tid == 0) *(int*)&khs[0][0][0] = atomicAdd(&ctr[s2], 1);
            __syncthreads();
            int it = *(const int*)&khs[0][0][0];
            __syncthreads();                       // all read it before overwrite
            if (it >= NIT_STREAM) break;
            int qt  = it & 7;
            int dir = (it >> 3) & 1;
            int b   = ((it >> 4) << 3) + s2;

            const u16 *qh_g, *kh_g, *vt_g;
            const int *qidx, *qcq, *qck;
            const float* vsp;
            float* ob;
            if (dir == 0) { qh_g=v1h; kh_g=v2h; vt_g=v2t;
                            qidx=qidx1; qcq=qcnt1; qck=qcnt2;
                            vsp = vsum + ((size_t)NB + b) * DD; ob = out; }
            else          { qh_g=v2h; kh_g=v1h; vt_g=v1t;
                            qidx=qidx2; qcq=qcnt2; qck=qcnt1;
                            vsp = vsum + (size_t)b * DD; ob = out + ELEMS; }
            int cnt_q = qcq[b];
            if (qt * BQ >= cnt_q) continue;
            int cnt_k = qck[b];
            int nkt2 = (cnt_k + 63) >> 6;

            int qslot = qt * BQ + w * 16 + lq;
            bool qvalid = qslot < cnt_q;

            const u16* qbh = qh_g + ((size_t)b * LL + qslot) * DD + g * 8;
            half8 qhf[8];
#pragma unroll
            for (int ks = 0; ks < 8; ++ks)
                qhf[ks] = *(const half8*)(const void*)(qbh + ks * 32);

            float m = MASK_FILL, z = 0.f;
            f32x4 o[16];
#pragma unroll
            for (int i2 = 0; i2 < 16; ++i2) o[i2] = (f32x4){0.f, 0.f, 0.f, 0.f};

            const size_t kv_base = (size_t)b * LL * DD;
            const size_t vt_base = (size_t)b * DD * LL;

            if (nkt2 > 0) {
                int cur = 0;
                STAGE(0, 0);
                asm volatile("s_waitcnt vmcnt(0)" ::: "memory");
                __builtin_amdgcn_s_barrier();
                __builtin_amdgcn_sched_barrier(0);

                for (int kt2 = 0; kt2 < nkt2; ++kt2) {
                    int k0 = kt2 * 64;
                    if (kt2 + 1 < nkt2) STAGE(cur ^ 1, kt2 + 1);

                    // S^T = K @ Q^T over 64 keys (2 halves x 2 row-tiles)
                    f32x4 sa[2][2];
#pragma unroll
                    for (int hh = 0; hh < 2; ++hh)
#pragma unroll
                        for (int rt = 0; rt < 2; ++rt)
                            sa[hh][rt] = (f32x4){0.f, 0.f, 0.f, 0.f};
                    __builtin_amdgcn_s_setprio(1);
#pragma unroll
                    for (int hh = 0; hh < 2; ++hh) {
#pragma unroll
                        for (int ks = 0; ks < 8; ++ks) {
                            int cidx = ((ks * 4 + g) ^ (lq & 7)) * 8;
                            half8 kh0 = *(const half8*)(const void*)&khs[cur][hh][lq * 256 + cidx];
                            half8 kh1 = *(const half8*)(const void*)&khs[cur][hh][(16 + lq) * 256 + cidx];
                            sa[hh][0] = __builtin_amdgcn_mfma_f32_16x16x32_f16(kh0, qhf[ks], sa[hh][0], 0, 0, 0);
                            sa[hh][1] = __builtin_amdgcn_mfma_f32_16x16x32_f16(kh1, qhf[ks], sa[hh][1], 0, 0, 0);
                        }
                    }
                    __builtin_amdgcn_s_setprio(0);

                    // preload PV A-fragments for dt=0..7 (latency under softmax)
                    half8 vfA[8], vfB[8];
#pragma unroll
                    for (int dt = 0; dt < 8; ++dt) {
                        int d = dt * 16 + lq;
                        vfA[dt] = *(const half8*)(const void*)&vts[cur][0][d * 32 + pvcc];
                        vfB[dt] = *(const half8*)(const void*)&vts[cur][1][d * 32 + pvcc];
                    }

                    float s[16];
#pragma unroll
                    for (int hh = 0; hh < 2; ++hh)
#pragma unroll
                        for (int i2 = 0; i2 < 4; ++i2) {
                            s[hh * 8 + i2]     = sa[hh][0][i2];
                            s[hh * 8 + 4 + i2] = sa[hh][1][i2];
                        }
                    if (kt2 == nkt2 - 1) {           // tail clamp: fake keys -> -inf
#pragma unroll
                        for (int hh = 0; hh < 2; ++hh) {
                            int base = k0 + hh * HB + 4 * g;
#pragma unroll
                            for (int i2 = 0; i2 < 4; ++i2) {
                                if (base + i2 >= cnt_k)      s[hh * 8 + i2]     = -1e30f;
                                if (base + 16 + i2 >= cnt_k) s[hh * 8 + 4 + i2] = -1e30f;
                            }
                        }
                    }
                    float pmax = s[0];
#pragma unroll
                    for (int i2 = 1; i2 < 16; ++i2) pmax = fmaxf(pmax, s[i2]);
                    pmax = fmaxf(pmax, __shfl_xor(pmax, 16));
                    pmax = fmaxf(pmax, __shfl_xor(pmax, 32));
                    if (__any(pmax > m + 8.f)) {     // T13 defer-max (exact)
                        float mnew = fmaxf(m, pmax);
                        float alpha = __expf(m - mnew);
                        z *= alpha;
#pragma unroll
                        for (int i2 = 0; i2 < 16; ++i2) o[i2] *= alpha;
                        m = mnew;
                    }
                    float p[16], psum = 0.f;
#pragma unroll
                    for (int i2 = 0; i2 < 16; ++i2) { p[i2] = __expf(s[i2] - m); psum += p[i2]; }
                    psum += __shfl_xor(psum, 16);
                    psum += __shfl_xor(psum, 32);
                    z += psum;

                    // P -> PV B-fragments (one per half), in-register exchange
                    union { unsigned u[4]; half8 v; } pf[2];
                    int srcA = ((lane & 16) << 1) | lq;
                    int srcB = srcA + 16;
                    bool sel = (g >> 1) != 0;
#pragma unroll
                    for (int hh = 0; hh < 2; ++hh) {
                        unsigned pk00 = pkf16(p[hh * 8 + 0], p[hh * 8 + 1]);
                        unsigned pk01 = pkf16(p[hh * 8 + 2], p[hh * 8 + 3]);
                        unsigned pk10 = pkf16(p[hh * 8 + 4], p[hh * 8 + 5]);
                        unsigned pk11 = pkf16(p[hh * 8 + 6], p[hh * 8 + 7]);
                        unsigned a00 = (unsigned)__shfl((int)pk00, srcA);
                        unsigned a01 = (unsigned)__shfl((int)pk01, srcA);
                        unsigned a10 = (unsigned)__shfl((int)pk10, srcA);
                        unsigned a11 = (unsigned)__shfl((int)pk11, srcA);
                        unsigned b00 = (unsigned)__shfl((int)pk00, srcB);
                        unsigned b01 = (unsigned)__shfl((int)pk01, srcB);
                        unsigned b10 = (unsigned)__shfl((int)pk10, srcB);
                        unsigned b11 = (unsigned)__shfl((int)pk11, srcB);
                        pf[hh].u[0] = sel ? a10 : a00;
                        pf[hh].u[1] = sel ? a11 : a01;
                        pf[hh].u[2] = sel ? b10 : b00;
                        pf[hh].u[3] = sel ? b11 : b01;
                    }

                    // O^T += V^T @ P^T: dt 0..7 from preloaded regs, 8..15 inline
                    __builtin_amdgcn_s_setprio(1);
#pragma unroll
                    for (int dt = 0; dt < 8; ++dt) {
                        o[dt] = __builtin_amdgcn_mfma_f32_16x16x32_f16(vfA[dt], pf[0].v, o[dt], 0, 0, 0);
                        o[dt] = __builtin_amdgcn_mfma_f32_16x16x32_f16(vfB[dt], pf[1].v, o[dt], 0, 0, 0);
                    }
#pragma unroll
                    for (int dt = 8; dt < 16; ++dt) {
                        int d = dt * 16 + lq;
                        half8 vf0 = *(const half8*)(const void*)&vts[cur][0][d * 32 + pvcc];
                        half8 vf1 = *(const half8*)(const void*)&vts[cur][1][d * 32 + pvcc];
                        o[dt] = __builtin_amdgcn_mfma_f32_16x16x32_f16(vf0, pf[0].v, o[dt], 0, 0, 0);
                        o[dt] = __builtin_amdgcn_mfma_f32_16x16x32_f16(vf1, pf[1].v, o[dt], 0, 0, 0);
                    }
                    __builtin_amdgcn_s_setprio(0);

                    if (kt2 + 1 < nkt2) {
                        asm volatile("s_waitcnt vmcnt(0)" ::: "memory");
                        __builtin_amdgcn_s_barrier();
                        __builtin_amdgcn_sched_barrier(0);
                    }
                    cur ^= 1;
                }
            }

            // exact masked-key lump: all masked logits == MASK_FILL
            float wl = __expf(MASK_FILL - m);      // m >= MASK_FILL always
            z += (float)(LL - cnt_k) * wl;
#pragma unroll
            for (int dt = 0; dt < 16; ++dt) {
                f32x4 vv = *(const f32x4*)(vsp + dt * 16 + 4 * g);
                o[dt] += wl * vv;
            }

            if (qvalid) {
                int qrow = qidx[b * LL + qslot];
                float zinv = 1.0f / z;
                float* orow = ob + ((size_t)b * LL + qrow) * DD + 4 * g;
#pragma unroll
                for (int dt = 0; dt < 16; ++dt) {
                    f32x4 vv = o[dt] * zinv;
                    *(f32x4*)(orow + dt * 16) = vv;
                }
            }
        }
    }
#undef STAGE
}

extern "C" void kernel_launch(void* const* d_in, const int* in_sizes, int n_in,
                              void* d_out, int out_size, void* d_ws, size_t ws_size,
                              hipStream_t stream)
{
    const float* v1      = (const float*)d_in[0];
    const void*  v1_mask = d_in[1];
    const float* v2      = (const float*)d_in[2];
    const void*  v2_mask = d_in[3];
    float* out = (float*)d_out;

    u16* v1h = (u16*)d_ws;           // compacted fp16 (row = compact slot)
    u16* v2h = v1h + ELEMS;
    u16* v1t = v2h + ELEMS;          // compacted fp16 transpose [b][d][slot]
    u16* v2t = v1t + ELEMS;
    int* qidx1 = (int*)(v2t + ELEMS);
    int* qcnt1 = qidx1 + NB * LL;
    int* qidx2 = qcnt1 + NB;
    int* qcnt2 = qidx2 + NB * LL;
    int* cm1   = qcnt2 + NB;
    int* cm2   = cm1 + NB * LL;
    int* pa1   = cm2 + NB * LL;
    int* pa2   = pa1 + NB * LL;
    int* ctr   = pa2 + NB * LL;                  // [8] steal counters
    float* part = (float*)(ctr + 16);            // [2][NB][16][256]
    float* vsum = part + 2 * NB * 16 * 256;      // [2][NB][256]

    prep_masks<<<dim3(128), dim3(256), 0, stream>>>(
        v1_mask, v2_mask, cm1, cm2,
        qidx1, pa1, qcnt1, qidx2, pa2, qcnt2, ctr);

    prep2_kernel<<<dim3(2 * NB * 64), dim3(256), 0, stream>>>(
        v1, v1h, v1t, cm1, pa1, qcnt1,
        v2, v2h, v2t, cm2, pa2, qcnt2, part, out);
    vsum_reduce<<<dim3(2 * NB), dim3(256), 0, stream>>>(part, vsum);

    // persistent, work-stealing fused flash (1 block/CU, 128KB LDS)
    flash_fused<<<dim3(256), dim3(512), 0, stream>>>(
        v1h, v2h, v1t, v2t,
        qidx1, qcnt1, qidx2, qcnt2, vsum, ctr, out);
}